// Round 17
// baseline (239.053 us; speedup 1.0000x reference)
//
#include <hip/hip_runtime.h>

// Problem dims
#define BB 8
#define LL 1024
#define DD 512
#define CC 4

typedef unsigned short u16;
typedef unsigned int u32;
typedef __attribute__((ext_vector_type(8))) short bf16x8;
typedef __attribute__((ext_vector_type(4))) float f32x4;
typedef __attribute__((ext_vector_type(4))) unsigned short u16x4;
typedef __attribute__((ext_vector_type(4))) float float4v;

typedef __attribute__((address_space(1))) const u32 gu32;
typedef __attribute__((address_space(3))) u32 lu32;
typedef __attribute__((address_space(3))) u16 l16;

__device__ __forceinline__ void gload16(const void* g, void* l) {
  __builtin_amdgcn_global_load_lds((gu32*)g, (lu32*)l, 16, 0, 0);
}
__device__ __forceinline__ u32 lds_off(const u16* p) {   // LDS byte offset
  return (u32)(uintptr_t)(l16*)p;
}

__device__ __forceinline__ u16 f2bf(float f) {
  unsigned u = __float_as_uint(f);
  u += 0x7FFF + ((u >> 16) & 1);   // round-to-nearest-even
  return (u16)(u >> 16);
}
__device__ __forceinline__ float bf2f(u16 h) {
  return __uint_as_float(((unsigned)h) << 16);
}
// saturation-safe fast tanh: 1 - 2/(e^{2x}+1)
__device__ __forceinline__ float fast_tanh(float x) {
  return 1.0f - 2.0f / (__expf(2.0f * x) + 1.0f);
}

// ---------------------------------------------------------------------------
// K0a: split fp32 X -> bf16 hi + bf16 lo
// ---------------------------------------------------------------------------
__global__ __launch_bounds__(256) void k_split(const float4v* __restrict__ x,
                                               u16* __restrict__ hi, u16* __restrict__ lo) {
  int i = blockIdx.x * 256 + threadIdx.x;
  float4v v = x[i];
  u16x4 h, l;
#pragma unroll
  for (int k = 0; k < 4; ++k) {
    u16 hh = f2bf(v[k]);
    h[k] = hh;
    l[k] = f2bf(v[k] - bf2f(hh));
  }
  *(u16x4*)&hi[(size_t)i * 4] = h;
  *(u16x4*)&lo[(size_t)i * 4] = l;
}

// ---------------------------------------------------------------------------
// K0b: transpose (C,D,D) weight and split to bf16 hi (+ optional lo)
// ---------------------------------------------------------------------------
__global__ __launch_bounds__(256) void k_tsplit(const float* __restrict__ w,
                                                u16* __restrict__ thi, u16* __restrict__ tlo) {
  __shared__ float t[32][33];
  int c = blockIdx.z;
  int tx = threadIdx.x;        // 0..31
  int ty = threadIdx.y;        // 0..7
  int e0 = blockIdx.x * 32, d0 = blockIdx.y * 32;
#pragma unroll
  for (int k = 0; k < 32; k += 8)
    t[ty + k][tx] = w[((size_t)c * DD + d0 + ty + k) * DD + e0 + tx];
  __syncthreads();
#pragma unroll
  for (int k = 0; k < 32; k += 8) {
    float v = t[tx][ty + k];
    size_t o = ((size_t)c * DD + e0 + ty + k) * DD + d0 + tx;
    u16 h = f2bf(v);
    thi[o] = h;
    if (tlo) tlo[o] = f2bf(v - bf2f(h));
  }
}

// ---------------------------------------------------------------------------
// 256x256-tile GEMM mainloop, BK=32, 4-DEEP buffers (counted-vmcnt engine):
// C = A(MxK)·B(NxK)^T, row-major stride 512.
// 512 threads = 8 waves (wr 0..1, wc 0..3); wave tile 128x64 = 8x4 frags,
// 32 MFMA per wave per step.
// LDS: [4][256][32] u16 per operand = 128 KB total (4 tracked K-tiles).
// Swizzle (R7-proven 4-slot): source xs=(tid&3)^((srow>>1)&3); read
// sidx = fq^((fr>>1)&3); linear DMA dest.
// R17 counted-vmcnt schedule (m218's T4 mechanism, the +38-73% lever):
//   prologue: STAGE(0),STAGE(1),STAGE(2)   [12 loads in flight]
//   iter t:   vmcnt(8)  [outstanding t,t+1,t+2=12 -> retires exactly t]
//             -> s_barrier -> STAGE_TOP(t+3) -> compute(t)
//                [STAGE_MID(t+3) spliced; wave ends lgkm(0)]
//   peels:    vmcnt(8) / vmcnt(4) / vmcnt(0)
// Loads are issued 3 steps (~3900cy) before their wait -> wait-stall ~0 even
// for HBM misses; loads stay in flight across barriers (never drained).
// WAR: STAGE(t+3) writes buf (t+3)&3, last read by compute(t-1) whose reads
// retired (wave-local lgkm0) before barrier t; stage issued after barrier t.
// SPLIT: 3 segments hi*hi + lo*hi + hi*lo (K-expanded 1536).
// ---------------------------------------------------------------------------
#define DSR(dst, addr, OFF) \
  asm volatile("ds_read_b128 %0, %1 offset:" #OFF : "=v"(dst) : "v"(addr))
#define LGKM(N) \
  do { __builtin_amdgcn_sched_barrier(0); \
       asm volatile("s_waitcnt lgkmcnt(" #N ")" ::: "memory"); \
       __builtin_amdgcn_sched_barrier(0); } while (0)
#define VMCNT(N) \
  do { __builtin_amdgcn_sched_barrier(0); \
       asm volatile("s_waitcnt vmcnt(" #N ")" ::: "memory"); \
       __builtin_amdgcn_sched_barrier(0); } while (0)

template<int NSEG, bool SPLIT>
__device__ __forceinline__ void gemm256(const u16* __restrict__ Ahi, const u16* __restrict__ Alo,
                                        const u16* __restrict__ Bhi, const u16* __restrict__ Blo,
                                        u16* lA, u16* lB, f32x4 (&acc)[8][4]) {
  const int tid = threadIdx.x;            // 0..511
  const int lane = tid & 63;
  const int wave = tid >> 6;              // 0..7
  const int wr = wave >> 2, wc = wave & 3;
  const int fr = lane & 15;
  const int fq = lane >> 4;               // quarter 0..3
  // staging: srow 0..127 (4 slots/row); issue pair covers rows srow, srow+128
  const int srow = tid >> 2;
  const int xs = (tid & 3) ^ ((srow >> 1) & 3);     // pre-swizzled source slot
  const size_t soff = (size_t)srow * DD + (size_t)xs * 8;
  // read addressing ([256][32] tile, 64B rows)
  const int sidx = fq ^ ((fr >> 1) & 3);
  const u32 ra = lds_off(lA) + (u32)((wr * 128 + fr) * 64 + sidx * 16);
  const u32 rb = lds_off(lB) + (u32)((wc * 64 + fr) * 64 + sidx * 16);

  const int NT = NSEG * 16;

  // beo: u16-elem offset of dest buffer {0,8192,16384,24576}
#define STAGE_TOP(T, beo) do {                                                \
    const int seg_ = SPLIT ? ((T) >> 4) : 0;                                  \
    const int kp_ = ((T) & 15) * 32;                                          \
    const u16* As_ = (SPLIT && seg_ == 1) ? Alo : Ahi;                        \
    const u16* Bs_ = (SPLIT && seg_ == 2) ? Blo : Bhi;                        \
    gload16(As_ + soff + kp_, lA + (beo) + tid * 8);                          \
    gload16(Bs_ + soff + kp_, lB + (beo) + tid * 8);                          \
  } while (0)

#define STAGE_MID(T, beo) do {                                                \
    const int seg_ = SPLIT ? ((T) >> 4) : 0;                                  \
    const int kp_ = ((T) & 15) * 32;                                          \
    const u16* As_ = (SPLIT && seg_ == 1) ? Alo : Ahi;                        \
    const u16* Bs_ = (SPLIT && seg_ == 2) ? Blo : Bhi;                        \
    gload16(As_ + soff + (size_t)128 * DD + kp_, lA + (beo) + tid * 8 + 4096); \
    gload16(Bs_ + soff + (size_t)128 * DD + kp_, lB + (beo) + tid * 8 + 4096); \
  } while (0)

#define STAGE_ALL(T, beo) do { STAGE_TOP(T, beo); STAGE_MID(T, beo); } while (0)

#define MFMA2(m0, m1) do {                                                    \
    _Pragma("unroll")                                                         \
    for (int ni = 0; ni < 4; ++ni)                                            \
      acc[m0][ni] = __builtin_amdgcn_mfma_f32_16x16x32_bf16(                  \
          af[m0], bv[ni], acc[m0][ni], 0, 0, 0);                              \
    _Pragma("unroll")                                                         \
    for (int ni = 0; ni < 4; ++ni)                                            \
      acc[m1][ni] = __builtin_amdgcn_mfma_f32_16x16x32_bf16(                  \
          af[m1], bv[ni], acc[m1][ni], 0, 0, 0);                              \
  } while (0)

  // peel-version compute: 12 ds_reads LGKM-pipelined vs 32 MFMA, no mid-issue
#define COMPUTE_PEEL(bo_) do {                                                \
    u32 aA_ = ra + (bo_), aB_ = rb + (bo_);                                   \
    bf16x8 af[8], bv[4];                                                      \
    DSR(bv[0], aB_, 0);    DSR(bv[1], aB_, 1024);                             \
    DSR(bv[2], aB_, 2048); DSR(bv[3], aB_, 3072);                             \
    DSR(af[0], aA_, 0);    DSR(af[1], aA_, 1024);                             \
    DSR(af[2], aA_, 2048); DSR(af[3], aA_, 3072);                             \
    LGKM(2);                                                                  \
    __builtin_amdgcn_s_setprio(1);                                            \
    MFMA2(0, 1);                                                              \
    DSR(af[4], aA_, 4096); DSR(af[5], aA_, 5120);                             \
    LGKM(2);                                                                  \
    MFMA2(2, 3);                                                              \
    DSR(af[6], aA_, 6144); DSR(af[7], aA_, 7168);                             \
    LGKM(2);                                                                  \
    MFMA2(4, 5);                                                              \
    LGKM(0);                                                                  \
    MFMA2(6, 7);                                                              \
    __builtin_amdgcn_s_setprio(0);                                            \
  } while (0)

  STAGE_ALL(0, 0);
  STAGE_ALL(1, 8192);
  STAGE_ALL(2, 16384);
  u32 beN = 24576;  // dest elems for tile t+3 (buf 3 at t=0)
  u32 bo = 0;       // read bytes for tile t (buf 0 at t=0)
#pragma unroll 1
  for (int t = 0; t < NT - 3; ++t) {
    VMCNT(8);                                          // retires exactly tile t
    __builtin_amdgcn_s_barrier();                      // data t ready block-wide
    __builtin_amdgcn_sched_barrier(0);
    STAGE_TOP(t + 3, beN);                             // into buf (t+3)&3
    {
      u32 aA_ = ra + bo, aB_ = rb + bo;
      bf16x8 af[8], bv[4];
      DSR(bv[0], aB_, 0);    DSR(bv[1], aB_, 1024);
      DSR(bv[2], aB_, 2048); DSR(bv[3], aB_, 3072);
      DSR(af[0], aA_, 0);    DSR(af[1], aA_, 1024);
      DSR(af[2], aA_, 2048); DSR(af[3], aA_, 3072);
      LGKM(2);
      __builtin_amdgcn_s_setprio(1);
      MFMA2(0, 1);
      DSR(af[4], aA_, 4096); DSR(af[5], aA_, 5120);
      LGKM(2);
      MFMA2(2, 3);
      STAGE_MID(t + 3, beN);                           // mid-step staging issue
      DSR(af[6], aA_, 6144); DSR(af[7], aA_, 7168);
      LGKM(2);
      MFMA2(4, 5);
      LGKM(0);                                         // reads retired (buf reusable)
      MFMA2(6, 7);
      __builtin_amdgcn_s_setprio(0);
    }
    beN = (beN + 8192) & 32767;
    bo = (bo + 16384u) & 65535u;
  }
  // peel NT-3: outstanding = t,t+1,t+2 = 12 -> vmcnt(8)
  VMCNT(8);
  __builtin_amdgcn_s_barrier();
  __builtin_amdgcn_sched_barrier(0);
  COMPUTE_PEEL(bo);
  bo = (bo + 16384u) & 65535u;
  // peel NT-2: outstanding = 8 -> vmcnt(4)
  VMCNT(4);
  __builtin_amdgcn_s_barrier();
  __builtin_amdgcn_sched_barrier(0);
  COMPUTE_PEEL(bo);
  bo = (bo + 16384u) & 65535u;
  // peel NT-1: outstanding = 4 -> vmcnt(0)
  VMCNT(0);
  __builtin_amdgcn_s_barrier();
  __builtin_amdgcn_sched_barrier(0);
  COMPUTE_PEEL(bo);
#undef STAGE_TOP
#undef STAGE_MID
#undef STAGE_ALL
#undef COMPUTE_PEEL
#undef MFMA2
}

// ---------------------------------------------------------------------------
// K1: mat_l[b,c] = X_b @ W_c  (split x split), epilogue splits result to bf16 hi/lo
// grid: 256 blocks (tm 0..3, tn 0..1 per bc), XCD-chunked decode
// ---------------------------------------------------------------------------
__global__ __launch_bounds__(512, 2) void k_matl(const u16* __restrict__ Xhi, const u16* __restrict__ Xlo,
                                                 const u16* __restrict__ Whi, const u16* __restrict__ Wlo,
                                                 u16* __restrict__ mhi, u16* __restrict__ mlo) {
  __shared__ u16 lA[4 * 256 * 32];
  __shared__ u16 lB[4 * 256 * 32];
  int lin = blockIdx.x;                       // 256
  int virt = (lin & 7) * 32 + (lin >> 3);     // XCD-chunked
  int bc = virt >> 3, rem = virt & 7;
  int tm = rem >> 1, tn = rem & 1;
  int b = bc >> 2, c = bc & 3;
  const u16* Ahi = Xhi + (size_t)b * LL * DD + (size_t)tm * 256 * DD;
  const u16* Alo = Xlo + (size_t)b * LL * DD + (size_t)tm * 256 * DD;
  const u16* Bhi = Whi + (size_t)c * DD * DD + (size_t)tn * 256 * DD;
  const u16* Blo = Wlo + (size_t)c * DD * DD + (size_t)tn * 256 * DD;
  f32x4 acc[8][4];
#pragma unroll
  for (int mi = 0; mi < 8; ++mi)
#pragma unroll
    for (int ni = 0; ni < 4; ++ni) acc[mi][ni] = (f32x4){0.f, 0.f, 0.f, 0.f};
  gemm256<3, true>(Ahi, Alo, Bhi, Blo, lA, lB, acc);

  int lane = threadIdx.x & 63, wave = threadIdx.x >> 6;
  int wr = wave >> 2, wc = wave & 3;
  int rgrp = (lane >> 4) * 4, cidx = lane & 15;
#pragma unroll
  for (int mi = 0; mi < 8; ++mi)
#pragma unroll
    for (int ni = 0; ni < 4; ++ni) {
      int row = tm * 256 + wr * 128 + mi * 16 + rgrp;
      int col = tn * 256 + wc * 64 + ni * 16 + cidx;
#pragma unroll
      for (int j = 0; j < 4; ++j) {
        float v = acc[mi][ni][j];
        size_t o = ((size_t)bc * LL + row + j) * DD + col;
        u16 h = f2bf(v);
        mhi[o] = h;
        mlo[o] = f2bf(v - bf2f(h));
      }
    }
}

// ---------------------------------------------------------------------------
// K2: s partials: per 256x256 tile of M = X_b @ mat_l[b,c]^T, tanh + row-sum
// grid: 512 blocks, XCD-chunked; s_part [bc][16][1024], slot = tn*4+wc
// ---------------------------------------------------------------------------
__global__ __launch_bounds__(512, 2) void k_s(const u16* __restrict__ Xhi, const u16* __restrict__ Xlo,
                                              const u16* __restrict__ mhi, const u16* __restrict__ mlo,
                                              const float* __restrict__ b_l, float* __restrict__ s_part) {
  __shared__ u16 lA[4 * 256 * 32];
  __shared__ u16 lB[4 * 256 * 32];
  int lin = blockIdx.x;                       // 512
  int virt = (lin & 7) * 64 + (lin >> 3);     // XCD-chunked
  int bc = virt >> 4, rem = virt & 15;
  int tm = rem >> 2, tn = rem & 3;
  int b = bc >> 2, c = bc & 3;
  const u16* Ahi = Xhi + (size_t)b * LL * DD + (size_t)tm * 256 * DD;
  const u16* Alo = Xlo + (size_t)b * LL * DD + (size_t)tm * 256 * DD;
  const u16* Bhi = mhi + (size_t)bc * LL * DD + (size_t)tn * 256 * DD;
  const u16* Blo = mlo + (size_t)bc * LL * DD + (size_t)tn * 256 * DD;
  f32x4 acc[8][4];
#pragma unroll
  for (int mi = 0; mi < 8; ++mi)
#pragma unroll
    for (int ni = 0; ni < 4; ++ni) acc[mi][ni] = (f32x4){0.f, 0.f, 0.f, 0.f};
  gemm256<3, true>(Ahi, Alo, Bhi, Blo, lA, lB, acc);

  int lane = threadIdx.x & 63, wave = threadIdx.x >> 6;
  int wr = wave >> 2, wc = wave & 3;
  float bl = b_l[c];
  float part[8][4];
#pragma unroll
  for (int mi = 0; mi < 8; ++mi)
#pragma unroll
    for (int j = 0; j < 4; ++j) part[mi][j] = 0.f;
#pragma unroll
  for (int mi = 0; mi < 8; ++mi)
#pragma unroll
    for (int ni = 0; ni < 4; ++ni)
#pragma unroll
      for (int j = 0; j < 4; ++j) part[mi][j] += fast_tanh(acc[mi][ni][j] + bl);
#pragma unroll
  for (int mi = 0; mi < 8; ++mi)
#pragma unroll
    for (int j = 0; j < 4; ++j) {
      float v = part[mi][j];
      v += __shfl_xor(v, 1, 64);
      v += __shfl_xor(v, 2, 64);
      v += __shfl_xor(v, 4, 64);
      v += __shfl_xor(v, 8, 64);
      part[mi][j] = v;
    }
  if ((lane & 15) == 0) {
    int slot = bc * 16 + tn * 4 + wc;
    int rg = (lane >> 4) * 4;
#pragma unroll
    for (int mi = 0; mi < 8; ++mi)
#pragma unroll
      for (int j = 0; j < 4; ++j) {
        int row = tm * 256 + wr * 128 + mi * 16 + rg + j;
        s_part[(size_t)slot * LL + row] = part[mi][j];
      }
  }
}

// ---------------------------------------------------------------------------
// K3: score_bar partials: sb = tanh(X_b @ w_v2[c] + b_v[c]), dot w_v1[c]
// grid: 256 blocks, XCD-chunked; sc_part [bc][8][1024], slot = tn*4+wc
// ---------------------------------------------------------------------------
__global__ __launch_bounds__(512, 2) void k_sbar(const u16* __restrict__ Xhi, const u16* __restrict__ Wv2T,
                                                 const float* __restrict__ b_v, const float* __restrict__ w_v1,
                                                 float* __restrict__ sc_part) {
  __shared__ u16 lA[4 * 256 * 32];
  __shared__ u16 lB[4 * 256 * 32];
  int lin = blockIdx.x;                       // 256
  int virt = (lin & 7) * 32 + (lin >> 3);
  int bc = virt >> 3, rem = virt & 7;
  int tm = rem >> 1, tn = rem & 1;
  int b = bc >> 2, c = bc & 3;
  const u16* Ahi = Xhi + (size_t)b * LL * DD + (size_t)tm * 256 * DD;
  const u16* Bhi = Wv2T + (size_t)c * DD * DD + (size_t)tn * 256 * DD;
  f32x4 acc[8][4];
#pragma unroll
  for (int mi = 0; mi < 8; ++mi)
#pragma unroll
    for (int ni = 0; ni < 4; ++ni) acc[mi][ni] = (f32x4){0.f, 0.f, 0.f, 0.f};
  gemm256<1, false>(Ahi, nullptr, Bhi, nullptr, lA, lB, acc);

  int lane = threadIdx.x & 63, wave = threadIdx.x >> 6;
  int wr = wave >> 2, wc = wave & 3;
  int cidx = lane & 15;
  float wv[4], bvv[4];
#pragma unroll
  for (int ni = 0; ni < 4; ++ni) {
    int col = tn * 256 + wc * 64 + ni * 16 + cidx;
    wv[ni] = w_v1[c * DD + col];
    bvv[ni] = b_v[c * DD + col];
  }
  float part[8][4];
#pragma unroll
  for (int mi = 0; mi < 8; ++mi)
#pragma unroll
    for (int j = 0; j < 4; ++j) part[mi][j] = 0.f;
#pragma unroll
  for (int mi = 0; mi < 8; ++mi)
#pragma unroll
    for (int ni = 0; ni < 4; ++ni)
#pragma unroll
      for (int j = 0; j < 4; ++j) part[mi][j] += fast_tanh(acc[mi][ni][j] + bvv[ni]) * wv[ni];
#pragma unroll
  for (int mi = 0; mi < 8; ++mi)
#pragma unroll
    for (int j = 0; j < 4; ++j) {
      float v = part[mi][j];
      v += __shfl_xor(v, 1, 64);
      v += __shfl_xor(v, 2, 64);
      v += __shfl_xor(v, 4, 64);
      v += __shfl_xor(v, 8, 64);
      part[mi][j] = v;
    }
  if ((lane & 15) == 0) {
    int slot = bc * 8 + tn * 4 + wc;
    int rg = (lane >> 4) * 4;
#pragma unroll
    for (int mi = 0; mi < 8; ++mi)
#pragma unroll
      for (int j = 0; j < 4; ++j) {
        int row = tm * 256 + wr * 128 + mi * 16 + rg + j;
        sc_part[(size_t)slot * LL + row] = part[mi][j];
      }
  }
}

// ---------------------------------------------------------------------------
// K4: softmaxes (a, a_bar) + pooled GEMV (integrated, measured-good).
// grid(32), block(1024)
// ---------------------------------------------------------------------------
__device__ __forceinline__ float blk_max(float v, float* red, int tid) {
#pragma unroll
  for (int m = 32; m >= 1; m >>= 1) v = fmaxf(v, __shfl_xor(v, m, 64));
  if ((tid & 63) == 0) red[tid >> 6] = v;
  __syncthreads();
  float r = red[0];
#pragma unroll
  for (int k = 1; k < 16; ++k) r = fmaxf(r, red[k]);
  __syncthreads();
  return r;
}
__device__ __forceinline__ float blk_sum(float v, float* red, int tid) {
#pragma unroll
  for (int m = 32; m >= 1; m >>= 1) v += __shfl_xor(v, m, 64);
  if ((tid & 63) == 0) red[tid >> 6] = v;
  __syncthreads();
  float r = red[0];
#pragma unroll
  for (int k = 1; k < 16; ++k) r += red[k];
  __syncthreads();
  return r;
}

__global__ __launch_bounds__(1024) void k_softmax(const float* __restrict__ s_part,
                                                  const float* __restrict__ sc_part,
                                                  const float* __restrict__ pad_k,
                                                  const float* __restrict__ X,
                                                  float* __restrict__ a_out,
                                                  float* __restrict__ abar_out,
                                                  float* __restrict__ pooled) {
  __shared__ float red[16];
  __shared__ float sm_abar[LL];
  __shared__ float pp[DD];
  int bc = blockIdx.x, b = bc >> 2;
  int i = threadIdx.x;
  float pk = pad_k[b * LL + i];

  float s = pk;
#pragma unroll
  for (int p = 0; p < 16; ++p) s += s_part[(size_t)(bc * 16 + p) * LL + i];
  float mx = blk_max(s, red, i);
  float e = expf(s - mx);
  float sum = blk_sum(e, red, i);
  float a = e / sum;
  a_out[bc * LL + i] = a;

  float sb = pk;
#pragma unroll
  for (int p = 0; p < 8; ++p) sb += sc_part[(size_t)(bc * 8 + p) * LL + i];
  float mx2 = blk_max(sb, red, i);
  float e2 = expf(sb - mx2);
  float sum2 = blk_sum(e2, red, i);
  float ab = e2 / sum2;
  abar_out[bc * LL + i] = ab;
  sm_abar[i] = ab;
  __syncthreads();

  // pooled GEMV over all 1024 threads: thread (h,d) sums half the L range
  {
    int d = i & (DD - 1), h = i >> 9;            // h in {0,1}
    const float* xb = X + (size_t)b * LL * DD + (size_t)h * 512 * DD + d;
    const float* abp = sm_abar + h * 512;
    float a0 = 0.f, a1 = 0.f, a2 = 0.f, a3 = 0.f;
    for (int l = 0; l < 512; l += 4) {
      a0 += abp[l + 0] * xb[(size_t)(l + 0) * DD];
      a1 += abp[l + 1] * xb[(size_t)(l + 1) * DD];
      a2 += abp[l + 2] * xb[(size_t)(l + 2) * DD];
      a3 += abp[l + 3] * xb[(size_t)(l + 3) * DD];
    }
    float sv = (a0 + a1) + (a2 + a3);
    if (h == 1) pp[d] = sv;
    __syncthreads();
    if (h == 0) pooled[bc * DD + d] = sv + pp[d];
  }
}

// ---------------------------------------------------------------------------
// K5: assemble C_features (B,L,D,5), coalesced via LDS repack.  grid(16384),256
// ---------------------------------------------------------------------------
__global__ __launch_bounds__(256) void k_assemble(const float* __restrict__ X,
                                                  const float* __restrict__ pad_k,
                                                  const float* __restrict__ a,
                                                  const float* __restrict__ pooled,
                                                  float* __restrict__ out) {
  __shared__ float buf[1280];
  int t = threadIdx.x;
  size_t idx = (size_t)blockIdx.x * 256 + t;   // flat (b,l,d)
  int d = (int)(idx & (DD - 1));
  int bl = (int)(idx >> 9);                    // b*L + l
  int b = bl >> 10;
  int l = bl & (LL - 1);
  float x = X[idx];
  float pk2 = (pad_k[bl] + 99999.0f) * (1.0f / 99999.0f);
#pragma unroll
  for (int c = 0; c < 4; ++c) {
    float av = a[(size_t)(b * 4 + c) * LL + l];
    float pv = pooled[(size_t)(b * 4 + c) * DD + d];
    buf[t * 5 + c] = av * x + pv * pk2;
  }
  buf[t * 5 + 4] = x;
  __syncthreads();
  size_t base = (size_t)blockIdx.x * 1280;
#pragma unroll
  for (int k = 0; k < 5; ++k) out[base + k * 256 + t] = buf[k * 256 + t];
}

// ---------------------------------------------------------------------------
extern "C" void kernel_launch(void* const* d_in, const int* in_sizes, int n_in,
                              void* d_out, int out_size, void* d_ws, size_t ws_size,
                              hipStream_t stream) {
  (void)in_sizes; (void)n_in; (void)out_size;
  const float* X     = (const float*)d_in[0];
  const float* pad_k = (const float*)d_in[1];
  const float* w_l   = (const float*)d_in[2];
  const float* b_l   = (const float*)d_in[3];
  const float* w_v1  = (const float*)d_in[4];
  const float* w_v2  = (const float*)d_in[5];
  const float* b_v   = (const float*)d_in[6];
  float* out = (float*)d_out;

  // Workspace layout (bytes). Xlo falls back into d_out's tail gap if ws small.
  char* wsp = (char*)d_ws;
  const size_t NEED = 26279936;
  bool small_ws = ws_size < NEED;
  u16* Xhi = (u16*)wsp;                                               // 8,388,608 B
  u16* Xlo = small_ws ? (u16*)((char*)d_out + 67108864)
                      : (u16*)(wsp + 8388608);                        // 8,388,608 B
  size_t off = small_ws ? 8388608 : 16777216;
  u16* WlThi = (u16*)(wsp + off);  off += 2097152;
  u16* WlTlo = (u16*)(wsp + off);  off += 2097152;
  u16* Wv2T  = (u16*)(wsp + off);  off += 2097152;
  float* s_part  = (float*)(wsp + off); off += 2097152;   // [32][16][1024] f32
  float* sc_part = (float*)(wsp + off); off += 1048576;   // [32][8][1024] f32
  float* pooled  = (float*)(wsp + off); off += 65536;     // [32][512] f32

  // mat_l hi/lo staged in d_out scratch (consumed before final writes).
  u16* mhi = (u16*)d_out;
  u16* mlo = (u16*)d_out + 16777216;

  float* a_out    = out + 20971520;   // (B,C,L,1)
  float* abar_out = out + 21004288;   // (B,C,L,1)

  k_split<<<4096, 256, 0, stream>>>((const float4v*)X, Xhi, Xlo);
  k_tsplit<<<dim3(16, 16, 4), dim3(32, 8), 0, stream>>>(w_l, WlThi, WlTlo);
  k_tsplit<<<dim3(16, 16, 4), dim3(32, 8), 0, stream>>>(w_v2, Wv2T, nullptr);

  k_matl<<<256, 512, 0, stream>>>(Xhi, Xlo, WlThi, WlTlo, mhi, mlo);
  k_s<<<512, 512, 0, stream>>>(Xhi, Xlo, mhi, mlo, b_l, s_part);
  k_sbar<<<256, 512, 0, stream>>>(Xhi, Wv2T, b_v, w_v1, sc_part);

  k_softmax<<<32, 1024, 0, stream>>>(s_part, sc_part, pad_k, X, a_out, abar_out, pooled);
  k_assemble<<<16384, 256, 0, stream>>>(X, pad_k, a_out, pooled, out);
}

// Round 18
// 214.247 us; speedup vs baseline: 1.1158x; 1.1158x over previous
//
#include <hip/hip_runtime.h>

// Problem dims
#define BB 8
#define LL 1024
#define DD 512
#define CC 4

typedef unsigned short u16;
typedef unsigned int u32;
typedef __attribute__((ext_vector_type(8))) short bf16x8;
typedef __attribute__((ext_vector_type(4))) float f32x4;
typedef __attribute__((ext_vector_type(4))) unsigned short u16x4;
typedef __attribute__((ext_vector_type(4))) float float4v;

typedef __attribute__((address_space(1))) const u32 gu32;
typedef __attribute__((address_space(3))) u32 lu32;
typedef __attribute__((address_space(3))) u16 l16;

__device__ __forceinline__ void gload16(const void* g, void* l) {
  __builtin_amdgcn_global_load_lds((gu32*)g, (lu32*)l, 16, 0, 0);
}
__device__ __forceinline__ u32 lds_off(const u16* p) {   // LDS byte offset
  return (u32)(uintptr_t)(l16*)p;
}

__device__ __forceinline__ u16 f2bf(float f) {
  unsigned u = __float_as_uint(f);
  u += 0x7FFF + ((u >> 16) & 1);   // round-to-nearest-even
  return (u16)(u >> 16);
}
__device__ __forceinline__ float bf2f(u16 h) {
  return __uint_as_float(((unsigned)h) << 16);
}
// saturation-safe fast tanh: 1 - 2/(e^{2x}+1)
__device__ __forceinline__ float fast_tanh(float x) {
  return 1.0f - 2.0f / (__expf(2.0f * x) + 1.0f);
}

// ---------------------------------------------------------------------------
// K0a: split fp32 X -> bf16 hi + bf16 lo
// ---------------------------------------------------------------------------
__global__ __launch_bounds__(256) void k_split(const float4v* __restrict__ x,
                                               u16* __restrict__ hi, u16* __restrict__ lo) {
  int i = blockIdx.x * 256 + threadIdx.x;
  float4v v = x[i];
  u16x4 h, l;
#pragma unroll
  for (int k = 0; k < 4; ++k) {
    u16 hh = f2bf(v[k]);
    h[k] = hh;
    l[k] = f2bf(v[k] - bf2f(hh));
  }
  *(u16x4*)&hi[(size_t)i * 4] = h;
  *(u16x4*)&lo[(size_t)i * 4] = l;
}

// ---------------------------------------------------------------------------
// K0b: transpose (C,D,D) weight and split to bf16 hi (+ optional lo)
// ---------------------------------------------------------------------------
__global__ __launch_bounds__(256) void k_tsplit(const float* __restrict__ w,
                                                u16* __restrict__ thi, u16* __restrict__ tlo) {
  __shared__ float t[32][33];
  int c = blockIdx.z;
  int tx = threadIdx.x;        // 0..31
  int ty = threadIdx.y;        // 0..7
  int e0 = blockIdx.x * 32, d0 = blockIdx.y * 32;
#pragma unroll
  for (int k = 0; k < 32; k += 8)
    t[ty + k][tx] = w[((size_t)c * DD + d0 + ty + k) * DD + e0 + tx];
  __syncthreads();
#pragma unroll
  for (int k = 0; k < 32; k += 8) {
    float v = t[tx][ty + k];
    size_t o = ((size_t)c * DD + e0 + ty + k) * DD + d0 + tx;
    u16 h = f2bf(v);
    thi[o] = h;
    if (tlo) tlo[o] = f2bf(v - bf2f(h));
  }
}

// ---------------------------------------------------------------------------
// 256x256-tile GEMM mainloop, BK=64 (R15-proven engine, best measured):
// C = A(MxK)·B(NxK)^T, row-major stride 512.  512 thr = 8 waves; wave tile
// 128x64 = 8x4 frags, 64 MFMA/wave/step (2 kk-halves of 32).
// DOUBLE-buffered LDS [2][256][64] u16 per operand = 128 KB total.
// Swizzle (both-sides, rule 21): phys_slot = logical ^ (row&7); linear DMA
// dest + inverse-swizzled SOURCE (xs = (tid&7)^((tid>>3)&7)); reads use
// p0 = fq^(fr&7), kk=1 via dk = ((p0^4)-p0)*16.
// One barrier per step:
//   step t: vmcnt(0) -> s_barrier -> STAGE_TOP(t+1) -> compute(t)
//           [STAGE_MID(t+1) spliced; each wave ends lgkmcnt(0)]
// SPLIT: 3 segments hi*hi + lo*hi + hi*lo (K-expanded 1536).
// ---------------------------------------------------------------------------
#define DSR(dst, addr, OFF) \
  asm volatile("ds_read_b128 %0, %1 offset:" #OFF : "=v"(dst) : "v"(addr))
#define LGKM(N) \
  do { __builtin_amdgcn_sched_barrier(0); \
       asm volatile("s_waitcnt lgkmcnt(" #N ")" ::: "memory"); \
       __builtin_amdgcn_sched_barrier(0); } while (0)

template<int NSEG, bool SPLIT>
__device__ __forceinline__ void gemm256(const u16* __restrict__ Ahi, const u16* __restrict__ Alo,
                                        const u16* __restrict__ Bhi, const u16* __restrict__ Blo,
                                        u16* lA, u16* lB, f32x4 (&acc)[8][4]) {
  const int tid = threadIdx.x;            // 0..511
  const int lane = tid & 63;
  const int wave = tid >> 6;              // 0..7
  const int wr = wave >> 2, wc = wave & 3;
  const int fr = lane & 15;
  const int fq = lane >> 4;               // quarter 0..3
  const int xs = (tid & 7) ^ ((tid >> 3) & 7);      // inverse-swizzled source slot
  const size_t soff = (size_t)(tid >> 3) * DD + (size_t)xs * 8;
  const int p0 = fq ^ (fr & 7);                     // phys slot for kk=0
  const int dk = ((p0 ^ 4) - p0) * 16;              // byte delta to kk=1 slot
  const u32 ra = lds_off(lA) + (u32)((wr * 128 + fr) * 128 + p0 * 16);
  const u32 rb = lds_off(lB) + (u32)((wc * 64 + fr) * 128 + p0 * 16);

  const int NT = NSEG * 8;

#define STAGE_TOP(T, beo) do {                                                \
    const int seg_ = SPLIT ? ((T) >> 3) : 0;                                  \
    const int kp_ = ((T) & 7) * 64;                                           \
    const u16* As_ = (SPLIT && seg_ == 1) ? Alo : Ahi;                        \
    const u16* Bs_ = (SPLIT && seg_ == 2) ? Blo : Bhi;                        \
    gload16(As_ + soff + kp_,                 lA + (beo) + tid * 8);          \
    gload16(Bs_ + soff + kp_,                 lB + (beo) + tid * 8);          \
    gload16(As_ + soff + (size_t)64 * DD + kp_, lA + (beo) + tid * 8 + 4096); \
    gload16(Bs_ + soff + (size_t)64 * DD + kp_, lB + (beo) + tid * 8 + 4096); \
  } while (0)

#define STAGE_MID(T, beo) do {                                                \
    const int seg_ = SPLIT ? ((T) >> 3) : 0;                                  \
    const int kp_ = ((T) & 7) * 64;                                           \
    const u16* As_ = (SPLIT && seg_ == 1) ? Alo : Ahi;                        \
    const u16* Bs_ = (SPLIT && seg_ == 2) ? Blo : Bhi;                        \
    gload16(As_ + soff + (size_t)128 * DD + kp_, lA + (beo) + tid * 8 + 8192);  \
    gload16(Bs_ + soff + (size_t)128 * DD + kp_, lB + (beo) + tid * 8 + 8192);  \
    gload16(As_ + soff + (size_t)192 * DD + kp_, lA + (beo) + tid * 8 + 12288); \
    gload16(Bs_ + soff + (size_t)192 * DD + kp_, lB + (beo) + tid * 8 + 12288); \
  } while (0)

#define MFMA2(m0, m1) do {                                                    \
    _Pragma("unroll")                                                         \
    for (int ni = 0; ni < 4; ++ni)                                            \
      acc[m0][ni] = __builtin_amdgcn_mfma_f32_16x16x32_bf16(                  \
          af[m0], bv[ni], acc[m0][ni], 0, 0, 0);                              \
    _Pragma("unroll")                                                         \
    for (int ni = 0; ni < 4; ++ni)                                            \
      acc[m1][ni] = __builtin_amdgcn_mfma_f32_16x16x32_bf16(                  \
          af[m1], bv[ni], acc[m1][ni], 0, 0, 0);                              \
  } while (0)

#define HALF(aA_, aB_) do {                                                   \
    bf16x8 af[8], bv[4];                                                      \
    DSR(bv[0], aB_, 0);    DSR(bv[1], aB_, 2048);                             \
    DSR(bv[2], aB_, 4096); DSR(bv[3], aB_, 6144);                             \
    DSR(af[0], aA_, 0);    DSR(af[1], aA_, 2048);                             \
    DSR(af[2], aA_, 4096); DSR(af[3], aA_, 6144);                             \
    LGKM(2);                                                                  \
    MFMA2(0, 1);                                                              \
    DSR(af[4], aA_, 8192); DSR(af[5], aA_, 10240);                            \
    LGKM(2);                                                                  \
    MFMA2(2, 3);                                                              \
    DSR(af[6], aA_, 12288); DSR(af[7], aA_, 14336);                           \
    LGKM(2);                                                                  \
    MFMA2(4, 5);                                                              \
    LGKM(0);                                                                  \
    MFMA2(6, 7);                                                              \
  } while (0)

#define HALF_MID(aA_, aB_, T, beo) do {                                       \
    bf16x8 af[8], bv[4];                                                      \
    DSR(bv[0], aB_, 0);    DSR(bv[1], aB_, 2048);                             \
    DSR(bv[2], aB_, 4096); DSR(bv[3], aB_, 6144);                             \
    DSR(af[0], aA_, 0);    DSR(af[1], aA_, 2048);                             \
    DSR(af[2], aA_, 4096); DSR(af[3], aA_, 6144);                             \
    LGKM(2);                                                                  \
    MFMA2(0, 1);                                                              \
    DSR(af[4], aA_, 8192); DSR(af[5], aA_, 10240);                            \
    LGKM(2);                                                                  \
    MFMA2(2, 3);                                                              \
    STAGE_MID(T, beo);                                                        \
    DSR(af[6], aA_, 12288); DSR(af[7], aA_, 14336);                           \
    LGKM(2);                                                                  \
    MFMA2(4, 5);                                                              \
    LGKM(0);                                                                  \
    MFMA2(6, 7);                                                              \
  } while (0)

  STAGE_TOP(0, 0);
  STAGE_MID(0, 0);
  int beN = 16384;  // dest elems for tile t+1 (buf 1 at t=0)
  u32 bo = 0;       // read bytes for tile t (buf 0 at t=0)
#pragma unroll 1
  for (int t = 0; t < NT - 1; ++t) {
    __builtin_amdgcn_sched_barrier(0);
    asm volatile("s_waitcnt vmcnt(0)" ::: "memory");   // tile t fully landed
    __builtin_amdgcn_sched_barrier(0);
    __builtin_amdgcn_s_barrier();                      // data ready + prev reads retired
    __builtin_amdgcn_sched_barrier(0);
    STAGE_TOP(t + 1, beN);                             // into other buf (safe post-barrier)
    {
      u32 aA0 = ra + bo, aB0 = rb + bo;
      __builtin_amdgcn_s_setprio(1);
      HALF_MID(aA0, aB0, t + 1, beN);                  // kk=0 + mid staging
      u32 aA1 = aA0 + dk, aB1 = aB0 + dk;
      HALF(aA1, aB1);                                  // kk=1
      __builtin_amdgcn_s_setprio(0);
    }
    beN ^= 16384;
    bo ^= 32768u;
  }
  // peel: last tile
  __builtin_amdgcn_sched_barrier(0);
  asm volatile("s_waitcnt vmcnt(0)" ::: "memory");
  __builtin_amdgcn_sched_barrier(0);
  __builtin_amdgcn_s_barrier();
  __builtin_amdgcn_sched_barrier(0);
  {
    u32 aA0 = ra + bo, aB0 = rb + bo;
    __builtin_amdgcn_s_setprio(1);
    HALF(aA0, aB0);
    u32 aA1 = aA0 + dk, aB1 = aB0 + dk;
    HALF(aA1, aB1);
    __builtin_amdgcn_s_setprio(0);
  }
#undef STAGE_TOP
#undef STAGE_MID
#undef HALF
#undef HALF_MID
#undef MFMA2
}

// ---------------------------------------------------------------------------
// K1: mat_l[b,c] = X_b @ W_c  (split x split), epilogue splits result to bf16 hi/lo
// grid: 256 blocks (tm 0..3, tn 0..1 per bc), XCD-chunked decode
// ---------------------------------------------------------------------------
__global__ __launch_bounds__(512, 2) void k_matl(const u16* __restrict__ Xhi, const u16* __restrict__ Xlo,
                                                 const u16* __restrict__ Whi, const u16* __restrict__ Wlo,
                                                 u16* __restrict__ mhi, u16* __restrict__ mlo) {
  __shared__ u16 lA[2 * 256 * 64];
  __shared__ u16 lB[2 * 256 * 64];
  int lin = blockIdx.x;                       // 256
  int virt = (lin & 7) * 32 + (lin >> 3);     // XCD-chunked
  int bc = virt >> 3, rem = virt & 7;
  int tm = rem >> 1, tn = rem & 1;
  int b = bc >> 2, c = bc & 3;
  const u16* Ahi = Xhi + (size_t)b * LL * DD + (size_t)tm * 256 * DD;
  const u16* Alo = Xlo + (size_t)b * LL * DD + (size_t)tm * 256 * DD;
  const u16* Bhi = Whi + (size_t)c * DD * DD + (size_t)tn * 256 * DD;
  const u16* Blo = Wlo + (size_t)c * DD * DD + (size_t)tn * 256 * DD;
  f32x4 acc[8][4];
#pragma unroll
  for (int mi = 0; mi < 8; ++mi)
#pragma unroll
    for (int ni = 0; ni < 4; ++ni) acc[mi][ni] = (f32x4){0.f, 0.f, 0.f, 0.f};
  gemm256<3, true>(Ahi, Alo, Bhi, Blo, lA, lB, acc);

  int lane = threadIdx.x & 63, wave = threadIdx.x >> 6;
  int wr = wave >> 2, wc = wave & 3;
  int rgrp = (lane >> 4) * 4, cidx = lane & 15;
#pragma unroll
  for (int mi = 0; mi < 8; ++mi)
#pragma unroll
    for (int ni = 0; ni < 4; ++ni) {
      int row = tm * 256 + wr * 128 + mi * 16 + rgrp;
      int col = tn * 256 + wc * 64 + ni * 16 + cidx;
#pragma unroll
      for (int j = 0; j < 4; ++j) {
        float v = acc[mi][ni][j];
        size_t o = ((size_t)bc * LL + row + j) * DD + col;
        u16 h = f2bf(v);
        mhi[o] = h;
        mlo[o] = f2bf(v - bf2f(h));
      }
    }
}

// ---------------------------------------------------------------------------
// K2: s partials: per 256x256 tile of M = X_b @ mat_l[b,c]^T, tanh + row-sum
// grid: 512 blocks, XCD-chunked; s_part [bc][16][1024], slot = tn*4+wc
// ---------------------------------------------------------------------------
__global__ __launch_bounds__(512, 2) void k_s(const u16* __restrict__ Xhi, const u16* __restrict__ Xlo,
                                              const u16* __restrict__ mhi, const u16* __restrict__ mlo,
                                              const float* __restrict__ b_l, float* __restrict__ s_part) {
  __shared__ u16 lA[2 * 256 * 64];
  __shared__ u16 lB[2 * 256 * 64];
  int lin = blockIdx.x;                       // 512
  int virt = (lin & 7) * 64 + (lin >> 3);     // XCD-chunked
  int bc = virt >> 4, rem = virt & 15;
  int tm = rem >> 2, tn = rem & 3;
  int b = bc >> 2, c = bc & 3;
  const u16* Ahi = Xhi + (size_t)b * LL * DD + (size_t)tm * 256 * DD;
  const u16* Alo = Xlo + (size_t)b * LL * DD + (size_t)tm * 256 * DD;
  const u16* Bhi = mhi + (size_t)bc * LL * DD + (size_t)tn * 256 * DD;
  const u16* Blo = mlo + (size_t)bc * LL * DD + (size_t)tn * 256 * DD;
  f32x4 acc[8][4];
#pragma unroll
  for (int mi = 0; mi < 8; ++mi)
#pragma unroll
    for (int ni = 0; ni < 4; ++ni) acc[mi][ni] = (f32x4){0.f, 0.f, 0.f, 0.f};
  gemm256<3, true>(Ahi, Alo, Bhi, Blo, lA, lB, acc);

  int lane = threadIdx.x & 63, wave = threadIdx.x >> 6;
  int wr = wave >> 2, wc = wave & 3;
  float bl = b_l[c];
  float part[8][4];
#pragma unroll
  for (int mi = 0; mi < 8; ++mi)
#pragma unroll
    for (int j = 0; j < 4; ++j) part[mi][j] = 0.f;
#pragma unroll
  for (int mi = 0; mi < 8; ++mi)
#pragma unroll
    for (int ni = 0; ni < 4; ++ni)
#pragma unroll
      for (int j = 0; j < 4; ++j) part[mi][j] += fast_tanh(acc[mi][ni][j] + bl);
#pragma unroll
  for (int mi = 0; mi < 8; ++mi)
#pragma unroll
    for (int j = 0; j < 4; ++j) {
      float v = part[mi][j];
      v += __shfl_xor(v, 1, 64);
      v += __shfl_xor(v, 2, 64);
      v += __shfl_xor(v, 4, 64);
      v += __shfl_xor(v, 8, 64);
      part[mi][j] = v;
    }
  if ((lane & 15) == 0) {
    int slot = bc * 16 + tn * 4 + wc;
    int rg = (lane >> 4) * 4;
#pragma unroll
    for (int mi = 0; mi < 8; ++mi)
#pragma unroll
      for (int j = 0; j < 4; ++j) {
        int row = tm * 256 + wr * 128 + mi * 16 + rg + j;
        s_part[(size_t)slot * LL + row] = part[mi][j];
      }
  }
}

// ---------------------------------------------------------------------------
// K3: score_bar partials: sb = tanh(X_b @ w_v2[c] + b_v[c]), dot w_v1[c]
// grid: 256 blocks, XCD-chunked; sc_part [bc][8][1024], slot = tn*4+wc
// ---------------------------------------------------------------------------
__global__ __launch_bounds__(512, 2) void k_sbar(const u16* __restrict__ Xhi, const u16* __restrict__ Wv2T,
                                                 const float* __restrict__ b_v, const float* __restrict__ w_v1,
                                                 float* __restrict__ sc_part) {
  __shared__ u16 lA[2 * 256 * 64];
  __shared__ u16 lB[2 * 256 * 64];
  int lin = blockIdx.x;                       // 256
  int virt = (lin & 7) * 32 + (lin >> 3);
  int bc = virt >> 3, rem = virt & 7;
  int tm = rem >> 1, tn = rem & 1;
  int b = bc >> 2, c = bc & 3;
  const u16* Ahi = Xhi + (size_t)b * LL * DD + (size_t)tm * 256 * DD;
  const u16* Bhi = Wv2T + (size_t)c * DD * DD + (size_t)tn * 256 * DD;
  f32x4 acc[8][4];
#pragma unroll
  for (int mi = 0; mi < 8; ++mi)
#pragma unroll
    for (int ni = 0; ni < 4; ++ni) acc[mi][ni] = (f32x4){0.f, 0.f, 0.f, 0.f};
  gemm256<1, false>(Ahi, nullptr, Bhi, nullptr, lA, lB, acc);

  int lane = threadIdx.x & 63, wave = threadIdx.x >> 6;
  int wr = wave >> 2, wc = wave & 3;
  int cidx = lane & 15;
  float wv[4], bvv[4];
#pragma unroll
  for (int ni = 0; ni < 4; ++ni) {
    int col = tn * 256 + wc * 64 + ni * 16 + cidx;
    wv[ni] = w_v1[c * DD + col];
    bvv[ni] = b_v[c * DD + col];
  }
  float part[8][4];
#pragma unroll
  for (int mi = 0; mi < 8; ++mi)
#pragma unroll
    for (int j = 0; j < 4; ++j) part[mi][j] = 0.f;
#pragma unroll
  for (int mi = 0; mi < 8; ++mi)
#pragma unroll
    for (int ni = 0; ni < 4; ++ni)
#pragma unroll
      for (int j = 0; j < 4; ++j) part[mi][j] += fast_tanh(acc[mi][ni][j] + bvv[ni]) * wv[ni];
#pragma unroll
  for (int mi = 0; mi < 8; ++mi)
#pragma unroll
    for (int j = 0; j < 4; ++j) {
      float v = part[mi][j];
      v += __shfl_xor(v, 1, 64);
      v += __shfl_xor(v, 2, 64);
      v += __shfl_xor(v, 4, 64);
      v += __shfl_xor(v, 8, 64);
      part[mi][j] = v;
    }
  if ((lane & 15) == 0) {
    int slot = bc * 8 + tn * 4 + wc;
    int rg = (lane >> 4) * 4;
#pragma unroll
    for (int mi = 0; mi < 8; ++mi)
#pragma unroll
      for (int j = 0; j < 4; ++j) {
        int row = tm * 256 + wr * 128 + mi * 16 + rg + j;
        sc_part[(size_t)slot * LL + row] = part[mi][j];
      }
  }
}

// ---------------------------------------------------------------------------
// K4: softmaxes (a, a_bar) ONLY.  grid(32), block(1024)
// ---------------------------------------------------------------------------
__device__ __forceinline__ float blk_max(float v, float* red, int tid) {
#pragma unroll
  for (int m = 32; m >= 1; m >>= 1) v = fmaxf(v, __shfl_xor(v, m, 64));
  if ((tid & 63) == 0) red[tid >> 6] = v;
  __syncthreads();
  float r = red[0];
#pragma unroll
  for (int k = 1; k < 16; ++k) r = fmaxf(r, red[k]);
  __syncthreads();
  return r;
}
__device__ __forceinline__ float blk_sum(float v, float* red, int tid) {
#pragma unroll
  for (int m = 32; m >= 1; m >>= 1) v += __shfl_xor(v, m, 64);
  if ((tid & 63) == 0) red[tid >> 6] = v;
  __syncthreads();
  float r = red[0];
#pragma unroll
  for (int k = 1; k < 16; ++k) r += red[k];
  __syncthreads();
  return r;
}

__global__ __launch_bounds__(1024) void k_softmax(const float* __restrict__ s_part,
                                                  const float* __restrict__ sc_part,
                                                  const float* __restrict__ pad_k,
                                                  float* __restrict__ a_out,
                                                  float* __restrict__ abar_out) {
  __shared__ float red[16];
  int bc = blockIdx.x, b = bc >> 2;
  int i = threadIdx.x;
  float pk = pad_k[b * LL + i];

  float s = pk;
#pragma unroll
  for (int p = 0; p < 16; ++p) s += s_part[(size_t)(bc * 16 + p) * LL + i];
  float mx = blk_max(s, red, i);
  float e = expf(s - mx);
  float sum = blk_sum(e, red, i);
  a_out[bc * LL + i] = e / sum;

  float sb = pk;
#pragma unroll
  for (int p = 0; p < 8; ++p) sb += sc_part[(size_t)(bc * 8 + p) * LL + i];
  float mx2 = blk_max(sb, red, i);
  float e2 = expf(sb - mx2);
  float sum2 = blk_sum(e2, red, i);
  abar_out[bc * LL + i] = e2 / sum2;
}

// ---------------------------------------------------------------------------
// K4b: pooled partials, X read ONCE: grid 256 = (b, L-chunk of 32), block 256.
// Each block reads 32 full rows (2 KB coalesced) of X_b and accumulates
// partials for ALL 4 channels.  ppool[(b*32+ch)*4 + c][512].
// ---------------------------------------------------------------------------
__global__ __launch_bounds__(256) void k_pool2(const float* __restrict__ abar,
                                               const float* __restrict__ X,
                                               float* __restrict__ ppool) {
  __shared__ float w[4][32];
  int blk = blockIdx.x;                 // 256 = b*32 + ch
  int b = blk >> 5, ch = blk & 31;
  int t = threadIdx.x;
  if (t < 128)
    w[t >> 5][t & 31] = abar[(size_t)(b * 4 + (t >> 5)) * LL + ch * 32 + (t & 31)];
  __syncthreads();
  const float* xb = X + (size_t)b * LL * DD + (size_t)ch * 32 * DD;
  float a0[4] = {0.f, 0.f, 0.f, 0.f}, a1[4] = {0.f, 0.f, 0.f, 0.f};
  for (int j = 0; j < 32; ++j) {
    float x0 = xb[(size_t)j * DD + t];
    float x1 = xb[(size_t)j * DD + t + 256];
#pragma unroll
    for (int c = 0; c < 4; ++c) {
      float wv = w[c][j];
      a0[c] += wv * x0;
      a1[c] += wv * x1;
    }
  }
  size_t base = (size_t)blk * 4 * DD;
#pragma unroll
  for (int c = 0; c < 4; ++c) {
    ppool[base + c * DD + t] = a0[c];
    ppool[base + c * DD + t + 256] = a1[c];
  }
}

// ---------------------------------------------------------------------------
// K4c: reduce pooled partials: grid 32 (bc), block 512.
// pooled[bc][d] = sum_ch ppool[(b*32+ch)*4 + c][d]
// ---------------------------------------------------------------------------
__global__ __launch_bounds__(512) void k_poolred(const float* __restrict__ ppool,
                                                 float* __restrict__ pooled) {
  int bc = blockIdx.x, b = bc >> 2, c = bc & 3;
  int d = threadIdx.x;
  float s = 0.f;
#pragma unroll 4
  for (int ch = 0; ch < 32; ++ch)
    s += ppool[((size_t)(b * 32 + ch) * 4 + c) * DD + d];
  pooled[bc * DD + d] = s;
}

// ---------------------------------------------------------------------------
// K5: assemble C_features (B,L,D,5), coalesced via LDS repack.  grid(16384),256
// ---------------------------------------------------------------------------
__global__ __launch_bounds__(256) void k_assemble(const float* __restrict__ X,
                                                  const float* __restrict__ pad_k,
                                                  const float* __restrict__ a,
                                                  const float* __restrict__ pooled,
                                                  float* __restrict__ out) {
  __shared__ float buf[1280];
  int t = threadIdx.x;
  size_t idx = (size_t)blockIdx.x * 256 + t;   // flat (b,l,d)
  int d = (int)(idx & (DD - 1));
  int bl = (int)(idx >> 9);                    // b*L + l
  int b = bl >> 10;
  int l = bl & (LL - 1);
  float x = X[idx];
  float pk2 = (pad_k[bl] + 99999.0f) * (1.0f / 99999.0f);
#pragma unroll
  for (int c = 0; c < 4; ++c) {
    float av = a[(size_t)(b * 4 + c) * LL + l];
    float pv = pooled[(size_t)(b * 4 + c) * DD + d];
    buf[t * 5 + c] = av * x + pv * pk2;
  }
  buf[t * 5 + 4] = x;
  __syncthreads();
  size_t base = (size_t)blockIdx.x * 1280;
#pragma unroll
  for (int k = 0; k < 5; ++k) out[base + k * 256 + t] = buf[k * 256 + t];
}

// ---------------------------------------------------------------------------
extern "C" void kernel_launch(void* const* d_in, const int* in_sizes, int n_in,
                              void* d_out, int out_size, void* d_ws, size_t ws_size,
                              hipStream_t stream) {
  (void)in_sizes; (void)n_in; (void)out_size;
  const float* X     = (const float*)d_in[0];
  const float* pad_k = (const float*)d_in[1];
  const float* w_l   = (const float*)d_in[2];
  const float* b_l   = (const float*)d_in[3];
  const float* w_v1  = (const float*)d_in[4];
  const float* w_v2  = (const float*)d_in[5];
  const float* b_v   = (const float*)d_in[6];
  float* out = (float*)d_out;

  // Workspace layout (bytes). Xlo falls back into d_out's tail gap if ws small.
  char* wsp = (char*)d_ws;
  const size_t NEED = 28377088;
  bool small_ws = ws_size < NEED;
  u16* Xhi = (u16*)wsp;                                               // 8,388,608 B
  u16* Xlo = small_ws ? (u16*)((char*)d_out + 67108864)
                      : (u16*)(wsp + 8388608);                        // 8,388,608 B
  size_t off = small_ws ? 8388608 : 16777216;
  u16* WlThi = (u16*)(wsp + off);  off += 2097152;
  u16* WlTlo = (u16*)(wsp + off);  off += 2097152;
  u16* Wv2T  = (u16*)(wsp + off);  off += 2097152;
  float* s_part  = (float*)(wsp + off); off += 2097152;   // [32][16][1024] f32
  float* sc_part = (float*)(wsp + off); off += 1048576;   // [32][8][1024] f32
  float* pooled  = (float*)(wsp + off); off += 65536;     // [32][512] f32
  float* ppool   = (float*)(wsp + off); off += 2097152;   // [256][4][512] f32

  // mat_l hi/lo staged in d_out scratch (consumed before final writes).
  u16* mhi = (u16*)d_out;
  u16* mlo = (u16*)d_out + 16777216;

  float* a_out    = out + 20971520;   // (B,C,L,1)
  float* abar_out = out + 21004288;   // (B,C,L,1)

  k_split<<<4096, 256, 0, stream>>>((const float4v*)X, Xhi, Xlo);
  k_tsplit<<<dim3(16, 16, 4), dim3(32, 8), 0, stream>>>(w_l, WlThi, WlTlo);
  k_tsplit<<<dim3(16, 16, 4), dim3(32, 8), 0, stream>>>(w_v2, Wv2T, nullptr);

  k_matl<<<256, 512, 0, stream>>>(Xhi, Xlo, WlThi, WlTlo, mhi, mlo);
  k_s<<<512, 512, 0, stream>>>(Xhi, Xlo, mhi, mlo, b_l, s_part);
  k_sbar<<<256, 512, 0, stream>>>(Xhi, Wv2T, b_v, w_v1, sc_part);

  k_softmax<<<32, 1024, 0, stream>>>(s_part, sc_part, pad_k, a_out, abar_out);
  k_pool2<<<256, 256, 0, stream>>>(abar_out, X, ppool);
  k_poolred<<<32, 512, 0, stream>>>(ppool, pooled);
  k_assemble<<<16384, 256, 0, stream>>>(X, pad_k, a_out, pooled, out);
}

// Round 19
// 208.875 us; speedup vs baseline: 1.1445x; 1.0257x over previous
//
#include <hip/hip_runtime.h>

// Problem dims
#define BB 8
#define LL 1024
#define DD 512
#define CC 4

typedef unsigned short u16;
typedef unsigned int u32;
typedef __attribute__((ext_vector_type(8))) short bf16x8;
typedef __attribute__((ext_vector_type(4))) float f32x4;
typedef __attribute__((ext_vector_type(4))) unsigned short u16x4;
typedef __attribute__((ext_vector_type(4))) float float4v;

typedef __attribute__((address_space(1))) const u32 gu32;
typedef __attribute__((address_space(3))) u32 lu32;
typedef __attribute__((address_space(3))) u16 l16;

__device__ __forceinline__ void gload16(const void* g, void* l) {
  __builtin_amdgcn_global_load_lds((gu32*)g, (lu32*)l, 16, 0, 0);
}
__device__ __forceinline__ u32 lds_off(const u16* p) {   // LDS byte offset
  return (u32)(uintptr_t)(l16*)p;
}

__device__ __forceinline__ u16 f2bf(float f) {
  unsigned u = __float_as_uint(f);
  u += 0x7FFF + ((u >> 16) & 1);   // round-to-nearest-even
  return (u16)(u >> 16);
}
__device__ __forceinline__ float bf2f(u16 h) {
  return __uint_as_float(((unsigned)h) << 16);
}
// saturation-safe fast tanh: 1 - 2/(e^{2x}+1)
__device__ __forceinline__ float fast_tanh(float x) {
  return 1.0f - 2.0f / (__expf(2.0f * x) + 1.0f);
}

// ---------------------------------------------------------------------------
// K0a: split fp32 X -> bf16 hi + bf16 lo
// ---------------------------------------------------------------------------
__global__ __launch_bounds__(256) void k_split(const float4v* __restrict__ x,
                                               u16* __restrict__ hi, u16* __restrict__ lo) {
  int i = blockIdx.x * 256 + threadIdx.x;
  float4v v = x[i];
  u16x4 h, l;
#pragma unroll
  for (int k = 0; k < 4; ++k) {
    u16 hh = f2bf(v[k]);
    h[k] = hh;
    l[k] = f2bf(v[k] - bf2f(hh));
  }
  *(u16x4*)&hi[(size_t)i * 4] = h;
  *(u16x4*)&lo[(size_t)i * 4] = l;
}

// ---------------------------------------------------------------------------
// K0b: transpose (C,D,D) weight and split to bf16 hi (+ optional lo)
// ---------------------------------------------------------------------------
__global__ __launch_bounds__(256) void k_tsplit(const float* __restrict__ w,
                                                u16* __restrict__ thi, u16* __restrict__ tlo) {
  __shared__ float t[32][33];
  int c = blockIdx.z;
  int tx = threadIdx.x;        // 0..31
  int ty = threadIdx.y;        // 0..7
  int e0 = blockIdx.x * 32, d0 = blockIdx.y * 32;
#pragma unroll
  for (int k = 0; k < 32; k += 8)
    t[ty + k][tx] = w[((size_t)c * DD + d0 + ty + k) * DD + e0 + tx];
  __syncthreads();
#pragma unroll
  for (int k = 0; k < 32; k += 8) {
    float v = t[tx][ty + k];
    size_t o = ((size_t)c * DD + e0 + ty + k) * DD + d0 + tx;
    u16 h = f2bf(v);
    thi[o] = h;
    if (tlo) tlo[o] = f2bf(v - bf2f(h));
  }
}

// ---------------------------------------------------------------------------
// 256x256-tile FUSED-SPLIT GEMM mainloop, BK=32, 16 K-tiles:
// acc += Ahi·Bhi^T + Alo·Bhi^T + Ahi·Blo^T  computed per K-tile (3 passes
// sharing staged panels) instead of 3 separate K-sweeps: staging bytes and
// ds_reads drop 33%, steps drop 24->16, MFMA unchanged.
// 512 thr = 8 waves (wr 0..1, wc 0..3); wave tile 128x64; 96 MFMA/wave/step
// (SPLIT) or 32 (!SPLIT).
// LDS (SPLIT): [2 buf][2 hi/lo][256][32] u16 per operand = 128 KB total.
// Swizzle (R17-validated 4-slot): source xs=(tid&3)^((srow>>1)&3); read
// sidx=fq^((fr>>1)&3); linear DMA dest.
// Schedule (R15-proven single barrier):
//   step t: vmcnt(0) [tile t's 8 loads only outstanding] -> s_barrier ->
//           STG_HI(t+1) -> pass1 hi*hi [STG_LO(t+1) mid] -> pass3 hi*lo
//           (af reused) -> pass2 lo*hi (bh reused); wave ends LGKM(0).
// ---------------------------------------------------------------------------
#define DSR(dst, addr, OFF) \
  asm volatile("ds_read_b128 %0, %1 offset:" #OFF : "=v"(dst) : "v"(addr))
#define LGKM(N) \
  do { __builtin_amdgcn_sched_barrier(0); \
       asm volatile("s_waitcnt lgkmcnt(" #N ")" ::: "memory"); \
       __builtin_amdgcn_sched_barrier(0); } while (0)

template<bool SPLIT>
__device__ __forceinline__ void gemm256f(const u16* __restrict__ Ahi, const u16* __restrict__ Alo,
                                         const u16* __restrict__ Bhi, const u16* __restrict__ Blo,
                                         u16* lA, u16* lB, f32x4 (&acc)[8][4]) {
  const int tid = threadIdx.x;            // 0..511
  const int lane = tid & 63;
  const int wave = tid >> 6;              // 0..7
  const int wr = wave >> 2, wc = wave & 3;
  const int fr = lane & 15;
  const int fq = lane >> 4;               // quarter 0..3
  const int srow = tid >> 2;              // 0..127
  const int xs = (tid & 3) ^ ((srow >> 1) & 3);     // pre-swizzled source slot
  const size_t soff = (size_t)srow * DD + (size_t)xs * 8;
  const int sidx = fq ^ ((fr >> 1) & 3);
  const u32 ra = lds_off(lA) + (u32)((wr * 128 + fr) * 64 + sidx * 16);
  const u32 rb = lds_off(lB) + (u32)((wc * 64 + fr) * 64 + sidx * 16);
  // buffer stride (bytes): SPLIT has hi+lo panels per buffer
  const u32 BUFB = SPLIT ? 32768u : 16384u;

#define STG_HI(T, beo) do {                                                   \
    const int kp_ = (T) * 32;                                                 \
    gload16(Ahi + soff + kp_,                  lA + (beo) + tid * 8);         \
    gload16(Ahi + soff + (size_t)128 * DD + kp_, lA + (beo) + tid * 8 + 4096);\
    gload16(Bhi + soff + kp_,                  lB + (beo) + tid * 8);         \
    gload16(Bhi + soff + (size_t)128 * DD + kp_, lB + (beo) + tid * 8 + 4096);\
  } while (0)

#define STG_LO(T, beo) do {                                                   \
    const int kp_ = (T) * 32;                                                 \
    gload16(Alo + soff + kp_,                  lA + (beo) + 8192 + tid * 8);  \
    gload16(Alo + soff + (size_t)128 * DD + kp_, lA + (beo) + 8192 + tid * 8 + 4096);\
    gload16(Blo + soff + kp_,                  lB + (beo) + 8192 + tid * 8);  \
    gload16(Blo + soff + (size_t)128 * DD + kp_, lB + (beo) + 8192 + tid * 8 + 4096);\
  } while (0)

#define MFMAC(A0, A1, BV) do {                                                \
    _Pragma("unroll")                                                         \
    for (int ni = 0; ni < 4; ++ni)                                            \
      acc[A0][ni] = __builtin_amdgcn_mfma_f32_16x16x32_bf16(                  \
          af[A0], BV[ni], acc[A0][ni], 0, 0, 0);                              \
    _Pragma("unroll")                                                         \
    for (int ni = 0; ni < 4; ++ni)                                            \
      acc[A1][ni] = __builtin_amdgcn_mfma_f32_16x16x32_bf16(                  \
          af[A1], BV[ni], acc[A1][ni], 0, 0, 0);                              \
  } while (0)
#define MFMAL(i0, i1, AL, BV) do {                                            \
    _Pragma("unroll")                                                         \
    for (int ni = 0; ni < 4; ++ni)                                            \
      acc[i0][ni] = __builtin_amdgcn_mfma_f32_16x16x32_bf16(                  \
          AL[0], BV[ni], acc[i0][ni], 0, 0, 0);                               \
    _Pragma("unroll")                                                         \
    for (int ni = 0; ni < 4; ++ni)                                            \
      acc[i1][ni] = __builtin_amdgcn_mfma_f32_16x16x32_bf16(                  \
          AL[1], BV[ni], acc[i1][ni], 0, 0, 0);                               \
  } while (0)

  // one full step's compute.  MIDSTAGE: 1 = issue STG_LO(tn, beN) mid-pass1.
#define COMP(bo_, MIDSTAGE, tn, beN_) do {                                    \
    u32 aH_ = ra + (bo_), bH_ = rb + (bo_);                                   \
    bf16x8 af[8], bh[4];                                                      \
    DSR(bh[0], bH_, 0);    DSR(bh[1], bH_, 1024);                             \
    DSR(bh[2], bH_, 2048); DSR(bh[3], bH_, 3072);                             \
    DSR(af[0], aH_, 0);    DSR(af[1], aH_, 1024);                             \
    DSR(af[2], aH_, 2048); DSR(af[3], aH_, 3072);                             \
    LGKM(2);                                                                  \
    __builtin_amdgcn_s_setprio(1);                                            \
    MFMAC(0, 1, bh);                                                          \
    DSR(af[4], aH_, 4096); DSR(af[5], aH_, 5120);                             \
    LGKM(2);                                                                  \
    MFMAC(2, 3, bh);                                                          \
    if (MIDSTAGE) { STG_LO(tn, beN_); }                                       \
    DSR(af[6], aH_, 6144); DSR(af[7], aH_, 7168);                             \
    LGKM(2);                                                                  \
    MFMAC(4, 5, bh);                                                          \
    LGKM(0);                                                                  \
    MFMAC(6, 7, bh);                                                          \
    if (SPLIT) {                                                              \
      /* pass3: hi*lo (af reused) */                                          \
      bf16x8 bl[4];                                                           \
      DSR(bl[0], bH_, 16384); DSR(bl[1], bH_, 17408);                         \
      DSR(bl[2], bH_, 18432); DSR(bl[3], bH_, 19456);                         \
      LGKM(0);                                                                \
      MFMAC(0, 1, bl); MFMAC(2, 3, bl);                                       \
      bf16x8 al0[2], al1[2], al2[2], al3[2];                                  \
      DSR(al0[0], aH_, 16384); DSR(al0[1], aH_, 17408);                       \
      DSR(al1[0], aH_, 18432); DSR(al1[1], aH_, 19456);                       \
      MFMAC(4, 5, bl); MFMAC(6, 7, bl);                                       \
      /* pass2: lo*hi (bh reused) */                                          \
      DSR(al2[0], aH_, 20480); DSR(al2[1], aH_, 21504);                       \
      DSR(al3[0], aH_, 22528); DSR(al3[1], aH_, 23552);                       \
      LGKM(4);                                                                \
      MFMAL(0, 1, al0, bh); MFMAL(2, 3, al1, bh);                             \
      LGKM(0);                                                                \
      MFMAL(4, 5, al2, bh); MFMAL(6, 7, al3, bh);                             \
    }                                                                         \
    __builtin_amdgcn_s_setprio(0);                                            \
  } while (0)

  STG_HI(0, 0);
  if (SPLIT) STG_LO(0, 0);
  u32 beN = SPLIT ? 16384u : 8192u;   // dest elems for tile t+1 (buf 1)
  u32 bo = 0;                          // read bytes for tile t (buf 0)
#pragma unroll 1
  for (int t = 0; t < 15; ++t) {
    __builtin_amdgcn_sched_barrier(0);
    asm volatile("s_waitcnt vmcnt(0)" ::: "memory");   // tile t fully landed
    __builtin_amdgcn_sched_barrier(0);
    __builtin_amdgcn_s_barrier();                      // data ready + prev reads retired
    __builtin_amdgcn_sched_barrier(0);
    STG_HI(t + 1, beN);                                // into other buf
    COMP(bo, SPLIT ? 1 : 0, t + 1, beN);
    beN ^= (SPLIT ? 16384u : 8192u);
    bo ^= BUFB;
  }
  // peel: last tile
  __builtin_amdgcn_sched_barrier(0);
  asm volatile("s_waitcnt vmcnt(0)" ::: "memory");
  __builtin_amdgcn_sched_barrier(0);
  __builtin_amdgcn_s_barrier();
  __builtin_amdgcn_sched_barrier(0);
  COMP(bo, 0, 0, 0u);
#undef STG_HI
#undef STG_LO
#undef COMP
#undef MFMAC
#undef MFMAL
}

// ---------------------------------------------------------------------------
// K1: mat_l[b,c] = X_b @ W_c  (fused split), epilogue splits result to bf16 hi/lo
// grid: 256 blocks (tm 0..3, tn 0..1 per bc), XCD-chunked decode
// ---------------------------------------------------------------------------
__global__ __launch_bounds__(512, 2) void k_matl(const u16* __restrict__ Xhi, const u16* __restrict__ Xlo,
                                                 const u16* __restrict__ Whi, const u16* __restrict__ Wlo,
                                                 u16* __restrict__ mhi, u16* __restrict__ mlo) {
  __shared__ u16 lA[2 * 2 * 256 * 32];
  __shared__ u16 lB[2 * 2 * 256 * 32];
  int lin = blockIdx.x;                       // 256
  int virt = (lin & 7) * 32 + (lin >> 3);     // XCD-chunked
  int bc = virt >> 3, rem = virt & 7;
  int tm = rem >> 1, tn = rem & 1;
  int b = bc >> 2, c = bc & 3;
  const u16* Ahi = Xhi + (size_t)b * LL * DD + (size_t)tm * 256 * DD;
  const u16* Alo = Xlo + (size_t)b * LL * DD + (size_t)tm * 256 * DD;
  const u16* Bhi = Whi + (size_t)c * DD * DD + (size_t)tn * 256 * DD;
  const u16* Blo = Wlo + (size_t)c * DD * DD + (size_t)tn * 256 * DD;
  f32x4 acc[8][4];
#pragma unroll
  for (int mi = 0; mi < 8; ++mi)
#pragma unroll
    for (int ni = 0; ni < 4; ++ni) acc[mi][ni] = (f32x4){0.f, 0.f, 0.f, 0.f};
  gemm256f<true>(Ahi, Alo, Bhi, Blo, lA, lB, acc);

  int lane = threadIdx.x & 63, wave = threadIdx.x >> 6;
  int wr = wave >> 2, wc = wave & 3;
  int rgrp = (lane >> 4) * 4, cidx = lane & 15;
#pragma unroll
  for (int mi = 0; mi < 8; ++mi)
#pragma unroll
    for (int ni = 0; ni < 4; ++ni) {
      int row = tm * 256 + wr * 128 + mi * 16 + rgrp;
      int col = tn * 256 + wc * 64 + ni * 16 + cidx;
#pragma unroll
      for (int j = 0; j < 4; ++j) {
        float v = acc[mi][ni][j];
        size_t o = ((size_t)bc * LL + row + j) * DD + col;
        u16 h = f2bf(v);
        mhi[o] = h;
        mlo[o] = f2bf(v - bf2f(h));
      }
    }
}

// ---------------------------------------------------------------------------
// K2: s partials: per 256x256 tile of M = X_b @ mat_l[b,c]^T, tanh + row-sum
// grid: 512 blocks, XCD-chunked; s_part [bc][16][1024], slot = tn*4+wc
// ---------------------------------------------------------------------------
__global__ __launch_bounds__(512, 2) void k_s(const u16* __restrict__ Xhi, const u16* __restrict__ Xlo,
                                              const u16* __restrict__ mhi, const u16* __restrict__ mlo,
                                              const float* __restrict__ b_l, float* __restrict__ s_part) {
  __shared__ u16 lA[2 * 2 * 256 * 32];
  __shared__ u16 lB[2 * 2 * 256 * 32];
  int lin = blockIdx.x;                       // 512
  int virt = (lin & 7) * 64 + (lin >> 3);     // XCD-chunked
  int bc = virt >> 4, rem = virt & 15;
  int tm = rem >> 2, tn = rem & 3;
  int b = bc >> 2, c = bc & 3;
  const u16* Ahi = Xhi + (size_t)b * LL * DD + (size_t)tm * 256 * DD;
  const u16* Alo = Xlo + (size_t)b * LL * DD + (size_t)tm * 256 * DD;
  const u16* Bhi = mhi + (size_t)bc * LL * DD + (size_t)tn * 256 * DD;
  const u16* Blo = mlo + (size_t)bc * LL * DD + (size_t)tn * 256 * DD;
  f32x4 acc[8][4];
#pragma unroll
  for (int mi = 0; mi < 8; ++mi)
#pragma unroll
    for (int ni = 0; ni < 4; ++ni) acc[mi][ni] = (f32x4){0.f, 0.f, 0.f, 0.f};
  gemm256f<true>(Ahi, Alo, Bhi, Blo, lA, lB, acc);

  int lane = threadIdx.x & 63, wave = threadIdx.x >> 6;
  int wr = wave >> 2, wc = wave & 3;
  float bl = b_l[c];
  float part[8][4];
#pragma unroll
  for (int mi = 0; mi < 8; ++mi)
#pragma unroll
    for (int j = 0; j < 4; ++j) part[mi][j] = 0.f;
#pragma unroll
  for (int mi = 0; mi < 8; ++mi)
#pragma unroll
    for (int ni = 0; ni < 4; ++ni)
#pragma unroll
      for (int j = 0; j < 4; ++j) part[mi][j] += fast_tanh(acc[mi][ni][j] + bl);
#pragma unroll
  for (int mi = 0; mi < 8; ++mi)
#pragma unroll
    for (int j = 0; j < 4; ++j) {
      float v = part[mi][j];
      v += __shfl_xor(v, 1, 64);
      v += __shfl_xor(v, 2, 64);
      v += __shfl_xor(v, 4, 64);
      v += __shfl_xor(v, 8, 64);
      part[mi][j] = v;
    }
  if ((lane & 15) == 0) {
    int slot = bc * 16 + tn * 4 + wc;
    int rg = (lane >> 4) * 4;
#pragma unroll
    for (int mi = 0; mi < 8; ++mi)
#pragma unroll
      for (int j = 0; j < 4; ++j) {
        int row = tm * 256 + wr * 128 + mi * 16 + rg + j;
        s_part[(size_t)slot * LL + row] = part[mi][j];
      }
  }
}

// ---------------------------------------------------------------------------
// K3: score_bar partials: sb = tanh(X_b @ w_v2[c] + b_v[c]), dot w_v1[c]
// grid: 256 blocks, XCD-chunked; sc_part [bc][8][1024], slot = tn*4+wc
// ---------------------------------------------------------------------------
__global__ __launch_bounds__(512, 2) void k_sbar(const u16* __restrict__ Xhi, const u16* __restrict__ Wv2T,
                                                 const float* __restrict__ b_v, const float* __restrict__ w_v1,
                                                 float* __restrict__ sc_part) {
  __shared__ u16 lA[2 * 256 * 32];
  __shared__ u16 lB[2 * 256 * 32];
  int lin = blockIdx.x;                       // 256
  int virt = (lin & 7) * 32 + (lin >> 3);
  int bc = virt >> 3, rem = virt & 7;
  int tm = rem >> 1, tn = rem & 1;
  int b = bc >> 2, c = bc & 3;
  const u16* Ahi = Xhi + (size_t)b * LL * DD + (size_t)tm * 256 * DD;
  const u16* Bhi = Wv2T + (size_t)c * DD * DD + (size_t)tn * 256 * DD;
  f32x4 acc[8][4];
#pragma unroll
  for (int mi = 0; mi < 8; ++mi)
#pragma unroll
    for (int ni = 0; ni < 4; ++ni) acc[mi][ni] = (f32x4){0.f, 0.f, 0.f, 0.f};
  gemm256f<false>(Ahi, nullptr, Bhi, nullptr, lA, lB, acc);

  int lane = threadIdx.x & 63, wave = threadIdx.x >> 6;
  int wr = wave >> 2, wc = wave & 3;
  int cidx = lane & 15;
  float wv[4], bvv[4];
#pragma unroll
  for (int ni = 0; ni < 4; ++ni) {
    int col = tn * 256 + wc * 64 + ni * 16 + cidx;
    wv[ni] = w_v1[c * DD + col];
    bvv[ni] = b_v[c * DD + col];
  }
  float part[8][4];
#pragma unroll
  for (int mi = 0; mi < 8; ++mi)
#pragma unroll
    for (int j = 0; j < 4; ++j) part[mi][j] = 0.f;
#pragma unroll
  for (int mi = 0; mi < 8; ++mi)
#pragma unroll
    for (int ni = 0; ni < 4; ++ni)
#pragma unroll
      for (int j = 0; j < 4; ++j) part[mi][j] += fast_tanh(acc[mi][ni][j] + bvv[ni]) * wv[ni];
#pragma unroll
  for (int mi = 0; mi < 8; ++mi)
#pragma unroll
    for (int j = 0; j < 4; ++j) {
      float v = part[mi][j];
      v += __shfl_xor(v, 1, 64);
      v += __shfl_xor(v, 2, 64);
      v += __shfl_xor(v, 4, 64);
      v += __shfl_xor(v, 8, 64);
      part[mi][j] = v;
    }
  if ((lane & 15) == 0) {
    int slot = bc * 8 + tn * 4 + wc;
    int rg = (lane >> 4) * 4;
#pragma unroll
    for (int mi = 0; mi < 8; ++mi)
#pragma unroll
      for (int j = 0; j < 4; ++j) {
        int row = tm * 256 + wr * 128 + mi * 16 + rg + j;
        sc_part[(size_t)slot * LL + row] = part[mi][j];
      }
  }
}

// ---------------------------------------------------------------------------
// K4: softmaxes (a, a_bar) ONLY.  grid(32), block(1024)
// ---------------------------------------------------------------------------
__device__ __forceinline__ float blk_max(float v, float* red, int tid) {
#pragma unroll
  for (int m = 32; m >= 1; m >>= 1) v = fmaxf(v, __shfl_xor(v, m, 64));
  if ((tid & 63) == 0) red[tid >> 6] = v;
  __syncthreads();
  float r = red[0];
#pragma unroll
  for (int k = 1; k < 16; ++k) r = fmaxf(r, red[k]);
  __syncthreads();
  return r;
}
__device__ __forceinline__ float blk_sum(float v, float* red, int tid) {
#pragma unroll
  for (int m = 32; m >= 1; m >>= 1) v += __shfl_xor(v, m, 64);
  if ((tid & 63) == 0) red[tid >> 6] = v;
  __syncthreads();
  float r = red[0];
#pragma unroll
  for (int k = 1; k < 16; ++k) r += red[k];
  __syncthreads();
  return r;
}

__global__ __launch_bounds__(1024) void k_softmax(const float* __restrict__ s_part,
                                                  const float* __restrict__ sc_part,
                                                  const float* __restrict__ pad_k,
                                                  float* __restrict__ a_out,
                                                  float* __restrict__ abar_out) {
  __shared__ float red[16];
  int bc = blockIdx.x, b = bc >> 2;
  int i = threadIdx.x;
  float pk = pad_k[b * LL + i];

  float s = pk;
#pragma unroll
  for (int p = 0; p < 16; ++p) s += s_part[(size_t)(bc * 16 + p) * LL + i];
  float mx = blk_max(s, red, i);
  float e = expf(s - mx);
  float sum = blk_sum(e, red, i);
  a_out[bc * LL + i] = e / sum;

  float sb = pk;
#pragma unroll
  for (int p = 0; p < 8; ++p) sb += sc_part[(size_t)(bc * 8 + p) * LL + i];
  float mx2 = blk_max(sb, red, i);
  float e2 = expf(sb - mx2);
  float sum2 = blk_sum(e2, red, i);
  abar_out[bc * LL + i] = e2 / sum2;
}

// ---------------------------------------------------------------------------
// K4b: pooled partials, X read ONCE: grid 256 = (b, L-chunk of 32), block 256.
// ---------------------------------------------------------------------------
__global__ __launch_bounds__(256) void k_pool2(const float* __restrict__ abar,
                                               const float* __restrict__ X,
                                               float* __restrict__ ppool) {
  __shared__ float w[4][32];
  int blk = blockIdx.x;                 // 256 = b*32 + ch
  int b = blk >> 5, ch = blk & 31;
  int t = threadIdx.x;
  if (t < 128)
    w[t >> 5][t & 31] = abar[(size_t)(b * 4 + (t >> 5)) * LL + ch * 32 + (t & 31)];
  __syncthreads();
  const float* xb = X + (size_t)b * LL * DD + (size_t)ch * 32 * DD;
  float a0[4] = {0.f, 0.f, 0.f, 0.f}, a1[4] = {0.f, 0.f, 0.f, 0.f};
  for (int j = 0; j < 32; ++j) {
    float x0 = xb[(size_t)j * DD + t];
    float x1 = xb[(size_t)j * DD + t + 256];
#pragma unroll
    for (int c = 0; c < 4; ++c) {
      float wv = w[c][j];
      a0[c] += wv * x0;
      a1[c] += wv * x1;
    }
  }
  size_t base = (size_t)blk * 4 * DD;
#pragma unroll
  for (int c = 0; c < 4; ++c) {
    ppool[base + c * DD + t] = a0[c];
    ppool[base + c * DD + t + 256] = a1[c];
  }
}

// ---------------------------------------------------------------------------
// K4c: reduce pooled partials: grid 32 (bc), block 512.
// ---------------------------------------------------------------------------
__global__ __launch_bounds__(512) void k_poolred(const float* __restrict__ ppool,
                                                 float* __restrict__ pooled) {
  int bc = blockIdx.x, b = bc >> 2, c = bc & 3;
  int d = threadIdx.x;
  float s = 0.f;
#pragma unroll 4
  for (int ch = 0; ch < 32; ++ch)
    s += ppool[((size_t)(b * 32 + ch) * 4 + c) * DD + d];
  pooled[bc * DD + d] = s;
}

// ---------------------------------------------------------------------------
// K5: assemble C_features (B,L,D,5), coalesced via LDS repack.  grid(16384),256
// ---------------------------------------------------------------------------
__global__ __launch_bounds__(256) void k_assemble(const float* __restrict__ X,
                                                  const float* __restrict__ pad_k,
                                                  const float* __restrict__ a,
                                                  const float* __restrict__ pooled,
                                                  float* __restrict__ out) {
  __shared__ float buf[1280];
  int t = threadIdx.x;
  size_t idx = (size_t)blockIdx.x * 256 + t;   // flat (b,l,d)
  int d = (int)(idx & (DD - 1));
  int bl = (int)(idx >> 9);                    // b*L + l
  int b = bl >> 10;
  int l = bl & (LL - 1);
  float x = X[idx];
  float pk2 = (pad_k[bl] + 99999.0f) * (1.0f / 99999.0f);
#pragma unroll
  for (int c = 0; c < 4; ++c) {
    float av = a[(size_t)(b * 4 + c) * LL + l];
    float pv = pooled[(size_t)(b * 4 + c) * DD + d];
    buf[t * 5 + c] = av * x + pv * pk2;
  }
  buf[t * 5 + 4] = x;
  __syncthreads();
  size_t base = (size_t)blockIdx.x * 1280;
#pragma unroll
  for (int k = 0; k < 5; ++k) out[base + k * 256 + t] = buf[k * 256 + t];
}

// ---------------------------------------------------------------------------
extern "C" void kernel_launch(void* const* d_in, const int* in_sizes, int n_in,
                              void* d_out, int out_size, void* d_ws, size_t ws_size,
                              hipStream_t stream) {
  (void)in_sizes; (void)n_in; (void)out_size;
  const float* X     = (const float*)d_in[0];
  const float* pad_k = (const float*)d_in[1];
  const float* w_l   = (const float*)d_in[2];
  const float* b_l   = (const float*)d_in[3];
  const float* w_v1  = (const float*)d_in[4];
  const float* w_v2  = (const float*)d_in[5];
  const float* b_v   = (const float*)d_in[6];
  float* out = (float*)d_out;

  // Workspace layout (bytes). Xlo falls back into d_out's tail gap if ws small.
  char* wsp = (char*)d_ws;
  const size_t NEED = 28377088;
  bool small_ws = ws_size < NEED;
  u16* Xhi = (u16*)wsp;                                               // 8,388,608 B
  u16* Xlo = small_ws ? (u16*)((char*)d_out + 67108864)
                      : (u16*)(wsp + 8388608);                        // 8,388,608 B
  size_t off = small_ws ? 8388608 : 16777216;
  u16* WlThi = (u16*)(wsp + off);  off += 2097152;
  u16* WlTlo = (u16*)(wsp + off);  off += 2097152;
  u16* Wv2T  = (u16*)(wsp + off);  off += 2097152;
  float* s_part  = (float*)(wsp + off); off += 2097152;   // [32][16][1024] f32
  float* sc_part = (float*)(wsp + off); off += 1048576;   // [32][8][1024] f32
  float* pooled  = (float*)(wsp + off); off += 65536;     // [32][512] f32
  float* ppool   = (float*)(wsp + off); off += 2097152;   // [256][4][512] f32

  // mat_l hi/lo staged in d_out scratch (consumed before final writes).
  u16* mhi = (u16*)d_out;
  u16* mlo = (u16*)d_out + 16777216;

  float* a_out    = out + 20971520;   // (B,C,L,1)
  float* abar_out = out + 21004288;   // (B,C,L,1)

  k_split<<<4096, 256, 0, stream>>>((const float4v*)X, Xhi, Xlo);
  k_tsplit<<<dim3(16, 16, 4), dim3(32, 8), 0, stream>>>(w_l, WlThi, WlTlo);
  k_tsplit<<<dim3(16, 16, 4), dim3(32, 8), 0, stream>>>(w_v2, Wv2T, nullptr);

  k_matl<<<256, 512, 0, stream>>>(Xhi, Xlo, WlThi, WlTlo, mhi, mlo);
  k_s<<<512, 512, 0, stream>>>(Xhi, Xlo, mhi, mlo, b_l, s_part);
  k_sbar<<<256, 512, 0, stream>>>(Xhi, Wv2T, b_v, w_v1, sc_part);

  k_softmax<<<32, 1024, 0, stream>>>(s_part, sc_part, pad_k, a_out, abar_out);
  k_pool2<<<256, 256, 0, stream>>>(abar_out, X, ppool);
  k_poolred<<<32, 512, 0, stream>>>(ppool, pooled);
  k_assemble<<<16384, 256, 0, stream>>>(X, pad_k, a_out, pooled, out);
}